// Round 5
// baseline (225.768 us; speedup 1.0000x reference)
//
#include <hip/hip_runtime.h>
#include <hip/hip_bf16.h>

// SchNet CFConv, MI355X gfx950 — round 8 (= round 7 resubmitted after infra
// failure; audited for OOB/capture hazards, none found):
//   * dRe pre-transformed to bf16 [10000][48][32] (dreb) by extra blocks of
//     kernel 1 -> cfconv stage1 A-frags are 3 coalesced aligned bf16x8 loads
//     (round-4's unaligned 100B-strided memcpy path was ~600 line-txns/block).
//     Pad columns g in [25,32) are ZEROED (0 x Inf = NaN hazard otherwise).
//   * f2out inlined as broadcast-A MFMA (y staged bf16 in LDS; A-frag is one
//     broadcast ds_read_b128; 8 MFMA; WoT frags issued after barrier A).
//   * stage2 + aggregation byte-identical to the measured-93us round-4 code.
//   * Host gates on ws_size >= 33.4 MB; fallback = exact round-4 kernels
//     (distinct names so rocprof shows which path ran).
//
// d_ws layout (unsigned short elements):
//   [0        .. 4096    )  W1T  bf16 [128 f][32 gpad]  (g>=25 zero)
//   [4096     .. 20480   )  W2T  bf16 [128 h][128 j]
//   [20480    .. 36864   )  WoT  bf16 [128 o][128 f]
//   [36864    .. 1316864 )  yfeatb bf16 [10000][128]
//   [1316864  .. 16676864)  dreb bf16 [10000][48][32]   (big-ws path only)

#define NA 10000
#define NK 48
#define NF 128
#define HP  136   // s_H  row pad (bf16): 272 B rows -> 2-way (free)
#define YFP 136   // s_yf row pad (bf16)

typedef __bf16 bf16x8 __attribute__((ext_vector_type(8)));
typedef float  f32x4  __attribute__((ext_vector_type(4)));

__device__ __forceinline__ unsigned short f2bs(float x) {
    return __builtin_bit_cast(unsigned short, (__bf16)x);
}
__device__ __forceinline__ float bs2f(unsigned short u) {
    return (float)__builtin_bit_cast(__bf16, u);
}
__device__ __forceinline__ float sspf(float v) {
    return fmaxf(v, 0.0f) + __logf(1.0f + __expf(-fabsf(v))) - 0.69314718056f;
}

// ---- kernel 1: in2f MFMA (blocks 0..156) + weight prep (157..300)
//      + dRe->dreb transform (301..1068, big-ws launch only) ----
__global__ __launch_bounds__(256) void in2f_prep(
    const float* __restrict__ x,
    const float* __restrict__ Wi,
    const float* __restrict__ W1,
    const float* __restrict__ W2,
    const float* __restrict__ Wo,
    const float* __restrict__ dRe,
    unsigned short* __restrict__ wsb,
    unsigned short* __restrict__ yfeatb,
    unsigned short* __restrict__ dreb)
{
    const int tid = threadIdx.x;

    if (blockIdx.x >= 301) {
        // ---- dreb transform: 3,000,000 float4 of dRe, grid-stride ----
        const float4* src = (const float4*)dRe;
        for (int j = (blockIdx.x - 301) * 256 + tid; j < 3000000; j += 768 * 256) {
            float4 v = src[j];
            int n  = j / 300;            // atom
            int rm = j - n * 300;        // float4 within atom
            int i  = rm * 4;             // element within atom
            int k  = i / 25;
            int g  = i - k * 25;
            unsigned short* dst = dreb + (size_t)n * 1536;
            float vv[4] = {v.x, v.y, v.z, v.w};
            #pragma unroll
            for (int e = 0; e < 4; ++e) {
                dst[k * 32 + g] = f2bs(vv[e]);
                if (++g == 25) {         // row k finished: zero its pad cols
                    #pragma unroll
                    for (int p = 25; p < 32; ++p) dst[k * 32 + p] = 0;
                    g = 0; ++k;
                }
            }
        }
        return;
    }

    if (blockIdx.x >= 157) {
        // ---- weight prep: 144 blocks x 256 = 36864 elements ----
        int i = (blockIdx.x - 157) * 256 + tid;
        if (i < 4096) {                       // W1T[f][g], g padded to 32
            int f = i >> 5, g = i & 31;
            wsb[i] = (g < 25) ? f2bs(W1[g * NF + f]) : (unsigned short)0;
        } else if (i < 20480) {               // W2T[h][j]
            int j = i - 4096; int h = j >> 7, k = j & 127;
            wsb[i] = f2bs(W2[k * NF + h]);
        } else {                              // WoT[o][f]
            int j = i - 20480; int f = j >> 7, k = j & 127;
            wsb[i] = f2bs(Wo[k * NF + f]);
        }
        return;
    }

    // ---- block-local Wi -> LDS transpose-convert: s_wi[f][i], pad 136 ----
    __shared__ __align__(16) unsigned short s_wi[NF * 136];   // 34816 B
    {
        const float4* wi4 = (const float4*)Wi;
        #pragma unroll
        for (int it = 0; it < 16; ++it) {
            int idx4 = it * 256 + tid;        // 4096 float4 = 128x128
            float4 v = wi4[idx4];
            int i = idx4 >> 5;                // row (i-dim)
            int f = (idx4 & 31) * 4;          // col start (f-dim)
            s_wi[(f + 0) * 136 + i] = f2bs(v.x);
            s_wi[(f + 1) * 136 + i] = f2bs(v.y);
            s_wi[(f + 2) * 136 + i] = f2bs(v.z);
            s_wi[(f + 3) * 136 + i] = f2bs(v.w);
        }
    }
    __syncthreads();

    const int w = tid >> 6;
    const int lane = tid & 63;
    const int r = lane & 15;
    const int q = lane >> 4;
    const int m0 = blockIdx.x * 64 + w * 16;
    const int row = m0 + r;
    const bool rv = (row < NA);

    f32x4 acc[8];
    #pragma unroll
    for (int nt = 0; nt < 8; ++nt) { acc[nt][0]=0.f; acc[nt][1]=0.f; acc[nt][2]=0.f; acc[nt][3]=0.f; }

    #pragma unroll
    for (int ks = 0; ks < 4; ++ks) {
        bf16x8 a;
        if (rv) {
            const float4* xp = (const float4*)(x + (size_t)row * NF + ks * 32 + q * 8);
            float4 v0 = xp[0], v1 = xp[1];
            a[0]=(__bf16)v0.x; a[1]=(__bf16)v0.y; a[2]=(__bf16)v0.z; a[3]=(__bf16)v0.w;
            a[4]=(__bf16)v1.x; a[5]=(__bf16)v1.y; a[6]=(__bf16)v1.z; a[7]=(__bf16)v1.w;
        } else {
            #pragma unroll
            for (int j = 0; j < 8; ++j) a[j] = (__bf16)0.0f;
        }
        #pragma unroll
        for (int nt = 0; nt < 8; ++nt) {
            bf16x8 b = *(const bf16x8*)(&s_wi[(nt * 16 + r) * 136 + ks * 32 + q * 8]);
            acc[nt] = __builtin_amdgcn_mfma_f32_16x16x32_bf16(a, b, acc[nt], 0, 0, 0);
        }
    }
    #pragma unroll
    for (int nt = 0; nt < 8; ++nt) {
        #pragma unroll
        for (int reg = 0; reg < 4; ++reg) {
            int orow = m0 + q * 4 + reg;
            if (orow < NA)
                yfeatb[(size_t)orow * NF + nt * 16 + r] = f2bs(acc[nt][reg]);
        }
    }
}

// ---- kernel 2 (primary): cfconv with direct dreb A-frags + inline f2out ----
__global__ __launch_bounds__(256) void cfconv_direct(
    const float* __restrict__ dR,
    const float* __restrict__ mask,
    const int*   __restrict__ nbr,
    const float* __restrict__ b1,
    const float* __restrict__ b2,
    const float* __restrict__ bf2o,
    const unsigned short* __restrict__ W1T,
    const unsigned short* __restrict__ W2T,
    const unsigned short* __restrict__ WoT,
    const unsigned short* __restrict__ dreb,
    const unsigned short* __restrict__ yfeatb,
    float* __restrict__ out)
{
    __shared__ __align__(16) unsigned short s_H[NK * HP];    // 13056 B
    __shared__ __align__(16) unsigned short s_yf[NK * YFP];  // 13056 B
    __shared__ __align__(16) unsigned short s_yb[NF];        // 256 B (y, bf16)
    __shared__ float s_cm[NK];

    const int tid = threadIdx.x;
    const int n = blockIdx.x;
    const int w = tid >> 6;
    const int lane = tid & 63;
    const int r = lane & 15;
    const int q = lane >> 4;
    const int nt0 = w * 2;        // this wave's two f-tiles

    // ---- prologue: issue all global loads ----
    const int kb = tid >> 4;
    const int sp = tid & 15;
    const int nb0 = nbr[n * NK + kb] * NF;
    const int nb1 = nbr[n * NK + kb + 16] * NF;
    const int nb2 = nbr[n * NK + kb + 32] * NF;
    bf16x8 g0 = *(const bf16x8*)(yfeatb + nb0 + sp * 8);
    bf16x8 g1 = *(const bf16x8*)(yfeatb + nb1 + sp * 8);
    bf16x8 g2 = *(const bf16x8*)(yfeatb + nb2 + sp * 8);

    // dreb A-frags: coalesced, 16B-aligned (pads zeroed at transform time)
    const unsigned short* dn = dreb + (size_t)n * 1536;
    bf16x8 a0 = *(const bf16x8*)(dn + (      r) * 32 + q * 8);
    bf16x8 a1 = *(const bf16x8*)(dn + (16  + r) * 32 + q * 8);
    bf16x8 a2 = *(const bf16x8*)(dn + (32  + r) * 32 + q * 8);

    bf16x8 bfr0 = *(const bf16x8*)(W1T + ((nt0    ) * 16 + r) * 32 + q * 8);
    bf16x8 bfr1 = *(const bf16x8*)(W1T + ((nt0 + 1) * 16 + r) * 32 + q * 8);
    bf16x8 bw[2][4];
    #pragma unroll
    for (int t = 0; t < 2; ++t)
        #pragma unroll
        for (int ks = 0; ks < 4; ++ks)
            bw[t][ks] = *(const bf16x8*)(W2T + ((nt0 + t) * 16 + r) * NF + ks * 32 + q * 8);

    if (tid < NK) {
        float d = dR[n * NK + tid];
        float m = mask[n * NK + tid];
        s_cm[tid] = (d <= 5.0f) ? m : 0.0f;
    }

    const float bias1a = b1[nt0 * 16 + r];
    const float bias1b = b1[nt0 * 16 + 16 + r];
    const float bias2a = b2[nt0 * 16 + r];
    const float bias2b = b2[nt0 * 16 + 16 + r];

    // ---- stage 1: H = ssp(dreb @ W1 + b1) ----
    #pragma unroll
    for (int mt = 0; mt < 3; ++mt) {
        bf16x8 av8 = (mt == 0) ? a0 : (mt == 1) ? a1 : a2;
        f32x4 zf; zf[0]=0.f; zf[1]=0.f; zf[2]=0.f; zf[3]=0.f;
        f32x4 h0v = __builtin_amdgcn_mfma_f32_16x16x32_bf16(av8, bfr0, zf, 0, 0, 0);
        f32x4 h1v = __builtin_amdgcn_mfma_f32_16x16x32_bf16(av8, bfr1, zf, 0, 0, 0);
        #pragma unroll
        for (int reg = 0; reg < 4; ++reg) {
            int k = mt * 16 + q * 4 + reg;
            s_H[k * HP + nt0 * 16 + r]      = f2bs(sspf(h0v[reg] + bias1a));
            s_H[k * HP + nt0 * 16 + 16 + r] = f2bs(sspf(h1v[reg] + bias1b));
        }
    }

    // ---- write gathered rows to LDS (latency hidden under stage1) ----
    *(bf16x8*)(&s_yf[(kb     ) * YFP + sp * 8]) = g0;
    *(bf16x8*)(&s_yf[(kb + 16) * YFP + sp * 8]) = g1;
    *(bf16x8*)(&s_yf[(kb + 32) * YFP + sp * 8]) = g2;

    __syncthreads();   // barrier A: s_H, s_yf, s_cm ready

    // ---- issue WoT frags early (consumed after barrier B) ----
    bf16x8 wo[2][4];
    #pragma unroll
    for (int t = 0; t < 2; ++t)
        #pragma unroll
        for (int ks = 0; ks < 4; ++ks)
            wo[t][ks] = *(const bf16x8*)(WoT + ((nt0 + t) * 16 + r) * NF + ks * 32 + q * 8);
    const float bo0 = bf2o[nt0 * 16 + r];
    const float bo1 = bf2o[nt0 * 16 + 16 + r];

    // ---- stage 2: A2 = H @ W2 (bias in epilogue) — round-4 code ----
    f32x4 acc[3][2];
    #pragma unroll
    for (int mt = 0; mt < 3; ++mt)
        #pragma unroll
        for (int t = 0; t < 2; ++t) { acc[mt][t][0]=0.f; acc[mt][t][1]=0.f; acc[mt][t][2]=0.f; acc[mt][t][3]=0.f; }

    #pragma unroll
    for (int ks = 0; ks < 4; ++ks) {
        #pragma unroll
        for (int mt = 0; mt < 3; ++mt) {
            bf16x8 ah = *(const bf16x8*)(&s_H[(mt * 16 + r) * HP + ks * 32 + q * 8]);
            acc[mt][0] = __builtin_amdgcn_mfma_f32_16x16x32_bf16(ah, bw[0][ks], acc[mt][0], 0, 0, 0);
            acc[mt][1] = __builtin_amdgcn_mfma_f32_16x16x32_bf16(ah, bw[1][ks], acc[mt][1], 0, 0, 0);
        }
    }

    // ---- gather + masked aggregation (round-4 code) ----
    float part0 = 0.f, part1 = 0.f;
    const int h0 = nt0 * 16 + r;
    #pragma unroll
    for (int mt = 0; mt < 3; ++mt) {
        #pragma unroll
        for (int reg = 0; reg < 4; ++reg) {
            int k = mt * 16 + q * 4 + reg;
            float cmk = s_cm[k];
            part0 += cmk * (acc[mt][0][reg] + bias2a) * bs2f(s_yf[k * YFP + h0]);
            part1 += cmk * (acc[mt][1][reg] + bias2b) * bs2f(s_yf[k * YFP + h0 + 16]);
        }
    }
    part0 += __shfl_xor(part0, 16);
    part0 += __shfl_xor(part0, 32);
    part1 += __shfl_xor(part1, 16);
    part1 += __shfl_xor(part1, 32);
    if (q == 0) {
        s_yb[h0]      = f2bs(part0);
        s_yb[h0 + 16] = f2bs(part1);
    }
    __syncthreads();   // barrier B: s_yb ready

    // ---- inline f2out: out = ssp(y @ Wf2o + b), broadcast-A MFMA ----
    f32x4 acco0, acco1;
    acco0[0]=0.f; acco0[1]=0.f; acco0[2]=0.f; acco0[3]=0.f;
    acco1[0]=0.f; acco1[1]=0.f; acco1[2]=0.f; acco1[3]=0.f;
    #pragma unroll
    for (int ks = 0; ks < 4; ++ks) {
        bf16x8 ya = *(const bf16x8*)(&s_yb[ks * 32 + q * 8]);  // broadcast over r
        acco0 = __builtin_amdgcn_mfma_f32_16x16x32_bf16(ya, wo[0][ks], acco0, 0, 0, 0);
        acco1 = __builtin_amdgcn_mfma_f32_16x16x32_bf16(ya, wo[1][ks], acco1, 0, 0, 0);
    }
    if (q == 0) {
        out[(size_t)n * NF + h0]      = sspf(acco0[0] + bo0);
        out[(size_t)n * NF + h0 + 16] = sspf(acco1[0] + bo1);
    }
}

// ==================== fallback path (exact round-4 kernels) ====================

__global__ __launch_bounds__(256) void cfconv_r4(
    const float* __restrict__ dR,
    const float* __restrict__ dRe,
    const float* __restrict__ mask,
    const int*   __restrict__ nbr,
    const float* __restrict__ b1,
    const float* __restrict__ b2,
    const unsigned short* __restrict__ W1T,
    const unsigned short* __restrict__ W2T,
    const unsigned short* __restrict__ yfeatb,
    float* __restrict__ yout)
{
    __shared__ __align__(16) unsigned short s_H[NK * HP];
    __shared__ __align__(16) unsigned short s_yf[NK * YFP];
    __shared__ float s_cm[NK];

    const int tid = threadIdx.x;
    const int n = blockIdx.x;
    const int w = tid >> 6;
    const int lane = tid & 63;
    const int r = lane & 15;
    const int q = lane >> 4;
    const int nt0 = w * 2;

    const int kb = tid >> 4;
    const int sp = tid & 15;
    const int nb0 = nbr[n * NK + kb] * NF;
    const int nb1 = nbr[n * NK + kb + 16] * NF;
    const int nb2 = nbr[n * NK + kb + 32] * NF;
    bf16x8 g0 = *(const bf16x8*)(yfeatb + nb0 + sp * 8);
    bf16x8 g1 = *(const bf16x8*)(yfeatb + nb1 + sp * 8);
    bf16x8 g2 = *(const bf16x8*)(yfeatb + nb2 + sp * 8);

    bf16x8 bfr0 = *(const bf16x8*)(W1T + ((nt0    ) * 16 + r) * 32 + q * 8);
    bf16x8 bfr1 = *(const bf16x8*)(W1T + ((nt0 + 1) * 16 + r) * 32 + q * 8);
    bf16x8 bw[2][4];
    #pragma unroll
    for (int t = 0; t < 2; ++t)
        #pragma unroll
        for (int ks = 0; ks < 4; ++ks)
            bw[t][ks] = *(const bf16x8*)(W2T + ((nt0 + t) * 16 + r) * NF + ks * 32 + q * 8);

    if (tid < NK) {
        float d = dR[n * NK + tid];
        float m = mask[n * NK + tid];
        s_cm[tid] = (d <= 5.0f) ? m : 0.0f;
    }

    const float bias1a = b1[nt0 * 16 + r];
    const float bias1b = b1[nt0 * 16 + 16 + r];
    const float bias2a = b2[nt0 * 16 + r];
    const float bias2b = b2[nt0 * 16 + 16 + r];

    const float* dre_n = dRe + (size_t)n * (NK * 25);
    #pragma unroll
    for (int mt = 0; mt < 3; ++mt) {
        bf16x8 av8;
        if (q < 3) {
            float av[8];
            __builtin_memcpy(av, dre_n + (mt * 16 + r) * 25 + q * 8, 32);
            #pragma unroll
            for (int j = 0; j < 8; ++j) av8[j] = (__bf16)av[j];
        } else {
            float v = dre_n[(mt * 16 + r) * 25 + 24];
            av8[0] = (__bf16)v;
            #pragma unroll
            for (int j = 1; j < 8; ++j) av8[j] = (__bf16)0.0f;
        }
        f32x4 zf; zf[0]=0.f; zf[1]=0.f; zf[2]=0.f; zf[3]=0.f;
        f32x4 h0v = __builtin_amdgcn_mfma_f32_16x16x32_bf16(av8, bfr0, zf, 0, 0, 0);
        f32x4 h1v = __builtin_amdgcn_mfma_f32_16x16x32_bf16(av8, bfr1, zf, 0, 0, 0);
        #pragma unroll
        for (int reg = 0; reg < 4; ++reg) {
            int k = mt * 16 + q * 4 + reg;
            s_H[k * HP + nt0 * 16 + r]      = f2bs(sspf(h0v[reg] + bias1a));
            s_H[k * HP + nt0 * 16 + 16 + r] = f2bs(sspf(h1v[reg] + bias1b));
        }
    }

    *(bf16x8*)(&s_yf[(kb     ) * YFP + sp * 8]) = g0;
    *(bf16x8*)(&s_yf[(kb + 16) * YFP + sp * 8]) = g1;
    *(bf16x8*)(&s_yf[(kb + 32) * YFP + sp * 8]) = g2;

    __syncthreads();

    f32x4 acc[3][2];
    #pragma unroll
    for (int mt = 0; mt < 3; ++mt)
        #pragma unroll
        for (int t = 0; t < 2; ++t) { acc[mt][t][0]=0.f; acc[mt][t][1]=0.f; acc[mt][t][2]=0.f; acc[mt][t][3]=0.f; }

    #pragma unroll
    for (int ks = 0; ks < 4; ++ks) {
        #pragma unroll
        for (int mt = 0; mt < 3; ++mt) {
            bf16x8 ah = *(const bf16x8*)(&s_H[(mt * 16 + r) * HP + ks * 32 + q * 8]);
            acc[mt][0] = __builtin_amdgcn_mfma_f32_16x16x32_bf16(ah, bw[0][ks], acc[mt][0], 0, 0, 0);
            acc[mt][1] = __builtin_amdgcn_mfma_f32_16x16x32_bf16(ah, bw[1][ks], acc[mt][1], 0, 0, 0);
        }
    }

    float part0 = 0.f, part1 = 0.f;
    const int h0 = nt0 * 16 + r;
    #pragma unroll
    for (int mt = 0; mt < 3; ++mt) {
        #pragma unroll
        for (int reg = 0; reg < 4; ++reg) {
            int k = mt * 16 + q * 4 + reg;
            float cmk = s_cm[k];
            part0 += cmk * (acc[mt][0][reg] + bias2a) * bs2f(s_yf[k * YFP + h0]);
            part1 += cmk * (acc[mt][1][reg] + bias2b) * bs2f(s_yf[k * YFP + h0 + 16]);
        }
    }
    part0 += __shfl_xor(part0, 16);
    part0 += __shfl_xor(part0, 32);
    part1 += __shfl_xor(part1, 16);
    part1 += __shfl_xor(part1, 32);
    if (q == 0) {
        yout[(size_t)n * NF + h0]      = part0;
        yout[(size_t)n * NF + h0 + 16] = part1;
    }
}

__global__ __launch_bounds__(256) void f2out_mfma(
    const unsigned short* __restrict__ WoT,
    const float* __restrict__ bo,
    float* io)
{
    const int tid = threadIdx.x;
    const int w = tid >> 6;
    const int lane = tid & 63;
    const int r = lane & 15;
    const int q = lane >> 4;
    const int m0 = blockIdx.x * 64 + w * 16;
    const int row = m0 + r;
    const bool rv = (row < NA);

    f32x4 acc[8];
    #pragma unroll
    for (int nt = 0; nt < 8; ++nt) { acc[nt][0]=0.f; acc[nt][1]=0.f; acc[nt][2]=0.f; acc[nt][3]=0.f; }

    #pragma unroll
    for (int ks = 0; ks < 4; ++ks) {
        bf16x8 a;
        if (rv) {
            const float4* yp = (const float4*)(io + (size_t)row * NF + ks * 32 + q * 8);
            float4 v0 = yp[0], v1 = yp[1];
            a[0]=(__bf16)v0.x; a[1]=(__bf16)v0.y; a[2]=(__bf16)v0.z; a[3]=(__bf16)v0.w;
            a[4]=(__bf16)v1.x; a[5]=(__bf16)v1.y; a[6]=(__bf16)v1.z; a[7]=(__bf16)v1.w;
        } else {
            #pragma unroll
            for (int j = 0; j < 8; ++j) a[j] = (__bf16)0.0f;
        }
        #pragma unroll
        for (int nt = 0; nt < 8; ++nt) {
            bf16x8 b = *(const bf16x8*)(WoT + (nt * 16 + r) * NF + ks * 32 + q * 8);
            acc[nt] = __builtin_amdgcn_mfma_f32_16x16x32_bf16(a, b, acc[nt], 0, 0, 0);
        }
    }
    #pragma unroll
    for (int nt = 0; nt < 8; ++nt) {
        float bia = bo[nt * 16 + r];
        #pragma unroll
        for (int reg = 0; reg < 4; ++reg) {
            int orow = m0 + q * 4 + reg;
            if (orow < NA)
                io[(size_t)orow * NF + nt * 16 + r] = sspf(acc[nt][reg] + bia);
        }
    }
}

extern "C" void kernel_launch(void* const* d_in, const int* in_sizes, int n_in,
                              void* d_out, int out_size, void* d_ws, size_t ws_size,
                              hipStream_t stream)
{
    const float* x    = (const float*)d_in[0];
    const float* dR   = (const float*)d_in[1];
    const float* dRe  = (const float*)d_in[2];
    const float* mask = (const float*)d_in[3];
    const int*   nbr  = (const int*)d_in[4];
    const float* W1   = (const float*)d_in[5];
    const float* b1   = (const float*)d_in[6];
    const float* W2   = (const float*)d_in[7];
    const float* b2   = (const float*)d_in[8];
    const float* Wi2f = (const float*)d_in[9];
    const float* Wf2o = (const float*)d_in[10];
    const float* bf2o = (const float*)d_in[11];
    float* out = (float*)d_out;

    unsigned short* wsb = (unsigned short*)d_ws;
    unsigned short* W1T    = wsb;              // 4096 elems
    unsigned short* W2T    = wsb + 4096;       // 16384 elems
    unsigned short* WoT    = wsb + 20480;      // 16384 elems
    unsigned short* yfeatb = wsb + 36864;      // 1,280,000 elems
    unsigned short* dreb   = wsb + 1316864;    // 15,360,000 elems (big path)

    const bool big = ws_size >= 33353728ULL;   // 16,676,864 shorts

    in2f_prep<<<big ? 1069 : 301, 256, 0, stream>>>(x, Wi2f, W1, W2, Wf2o, dRe,
                                                    wsb, yfeatb, dreb);
    if (big) {
        cfconv_direct<<<NA, 256, 0, stream>>>(dR, mask, nbr, b1, b2, bf2o,
                                              W1T, W2T, WoT, dreb, yfeatb, out);
    } else {
        cfconv_r4<<<NA, 256, 0, stream>>>(dR, dRe, mask, nbr, b1, b2,
                                          W1T, W2T, yfeatb, out);
        f2out_mfma<<<157, 256, 0, stream>>>(WoT, bf2o, out);
    }
}

// Round 6
// 197.209 us; speedup vs baseline: 1.1448x; 1.1448x over previous
//
#include <hip/hip_runtime.h>
#include <hip/hip_bf16.h>

// SchNet CFConv, MI355X gfx950 — round 9: revert to the measured-198us
// round-4 4-kernel config (prep_weights / in2f WiT-global / cfconv / f2out),
// with ONE change: cfconv at 128 threads (2 waves), each wave owning 4
// f-tiles. Halves total waves 40000 -> 20000 against the observed
// ~400 waves/us completion ceiling, per-block LDS unchanged (6 blocks/CU).
// dreb and inline-f2out dropped (r8: net losers).
//
// d_ws layout (unsigned short elements):
//   [0      .. 4096  )  W1T  bf16 [128 f][32 gpad]   (g>=25 zero)
//   [4096   .. 20480 )  W2T  bf16 [128 h][128 j]
//   [20480  .. 36864 )  WiT  bf16 [128 f][128 i]
//   [36864  .. 53248 )  WoT  bf16 [128 o][128 f]
//   [53248  .. +1.28M)  yfeatb bf16 [10000][128]

#define NA 10000
#define NK 48
#define NF 128
#define HP  136   // s_H  row pad (bf16): 272 B rows -> 2-way (free)
#define YFP 136   // s_yf row pad (bf16)

typedef __bf16 bf16x8 __attribute__((ext_vector_type(8)));
typedef float  f32x4  __attribute__((ext_vector_type(4)));

__device__ __forceinline__ unsigned short f2bs(float x) {
    return __builtin_bit_cast(unsigned short, (__bf16)x);
}
__device__ __forceinline__ float bs2f(unsigned short u) {
    return (float)__builtin_bit_cast(__bf16, u);
}
__device__ __forceinline__ float sspf(float v) {
    return fmaxf(v, 0.0f) + __logf(1.0f + __expf(-fabsf(v))) - 0.69314718056f;
}

// ---- setup: transpose-convert weights to bf16 in d_ws ----
__global__ __launch_bounds__(256) void prep_weights(
    const float* __restrict__ W1,
    const float* __restrict__ W2,
    const float* __restrict__ Wi,
    const float* __restrict__ Wo,
    unsigned short* __restrict__ wsb)
{
    int i = blockIdx.x * 256 + threadIdx.x;
    if (i < 4096) {                       // W1T[f][g], g padded to 32
        int f = i >> 5, g = i & 31;
        wsb[i] = (g < 25) ? f2bs(W1[g * NF + f]) : (unsigned short)0;
    } else if (i < 20480) {               // W2T[h][j]
        int j = i - 4096; int h = j >> 7, k = j & 127;
        wsb[i] = f2bs(W2[k * NF + h]);
    } else if (i < 36864) {               // WiT[f][i]
        int j = i - 20480; int f = j >> 7, k = j & 127;
        wsb[i] = f2bs(Wi[k * NF + f]);
    } else if (i < 53248) {               // WoT[o][f]
        int j = i - 36864; int f = j >> 7, k = j & 127;
        wsb[i] = f2bs(Wo[k * NF + f]);
    }
}

// ---- in2f: yfeatb = bf16( x @ W_in2f ), MFMA, 64 rows/block ----
__global__ __launch_bounds__(256) void in2f_mfma(
    const float* __restrict__ x,
    const unsigned short* __restrict__ WiT,
    unsigned short* __restrict__ yfeatb)
{
    const int tid = threadIdx.x;
    const int w = tid >> 6;
    const int lane = tid & 63;
    const int r = lane & 15;
    const int q = lane >> 4;
    const int m0 = blockIdx.x * 64 + w * 16;
    const int row = m0 + r;
    const bool rv = (row < NA);

    f32x4 acc[8];
    #pragma unroll
    for (int nt = 0; nt < 8; ++nt) { acc[nt][0]=0.f; acc[nt][1]=0.f; acc[nt][2]=0.f; acc[nt][3]=0.f; }

    #pragma unroll
    for (int ks = 0; ks < 4; ++ks) {
        bf16x8 a;
        if (rv) {
            const float4* xp = (const float4*)(x + (size_t)row * NF + ks * 32 + q * 8);
            float4 v0 = xp[0], v1 = xp[1];
            a[0]=(__bf16)v0.x; a[1]=(__bf16)v0.y; a[2]=(__bf16)v0.z; a[3]=(__bf16)v0.w;
            a[4]=(__bf16)v1.x; a[5]=(__bf16)v1.y; a[6]=(__bf16)v1.z; a[7]=(__bf16)v1.w;
        } else {
            #pragma unroll
            for (int j = 0; j < 8; ++j) a[j] = (__bf16)0.0f;
        }
        #pragma unroll
        for (int nt = 0; nt < 8; ++nt) {
            bf16x8 b = *(const bf16x8*)(WiT + (nt * 16 + r) * NF + ks * 32 + q * 8);
            acc[nt] = __builtin_amdgcn_mfma_f32_16x16x32_bf16(a, b, acc[nt], 0, 0, 0);
        }
    }
    #pragma unroll
    for (int nt = 0; nt < 8; ++nt) {
        #pragma unroll
        for (int reg = 0; reg < 4; ++reg) {
            int orow = m0 + q * 4 + reg;
            if (orow < NA)
                yfeatb[(size_t)orow * NF + nt * 16 + r] = f2bs(acc[nt][reg]);
        }
    }
}

// ---- cfconv: 128 threads / 2 waves, each wave owns 4 f-tiles ----
__global__ __launch_bounds__(128, 3) void cfconv_d(
    const float* __restrict__ dR,
    const float* __restrict__ dRe,
    const float* __restrict__ mask,
    const int*   __restrict__ nbr,
    const float* __restrict__ b1,
    const float* __restrict__ b2,
    const unsigned short* __restrict__ W1T,
    const unsigned short* __restrict__ W2T,
    const unsigned short* __restrict__ yfeatb,
    float* __restrict__ yout)
{
    __shared__ __align__(16) unsigned short s_H[NK * HP];    // 13056 B
    __shared__ __align__(16) unsigned short s_yf[NK * YFP];  // 13056 B
    __shared__ float s_cm[NK];                               // 192 B

    const int tid = threadIdx.x;     // [0,128)
    const int n = blockIdx.x;
    const int w = tid >> 6;          // wave 0/1
    const int lane = tid & 63;
    const int r = lane & 15;
    const int q = lane >> 4;
    const int ft0 = w * 4;           // this wave's four f-tiles

    // ---- issue neighbor-row gather loads (6 rows/thread) ----
    const int kb = tid >> 4;         // [0,8)
    const int sp = tid & 15;         // 16B slot within row
    bf16x8 g[6];
    #pragma unroll
    for (int j = 0; j < 6; ++j) {
        int base = nbr[n * NK + kb + 8 * j] * NF;
        g[j] = *(const bf16x8*)(yfeatb + base + sp * 8);
    }

    // ---- preload W1 fragments for 4 f-tiles ----
    bf16x8 bfr[4];
    #pragma unroll
    for (int t = 0; t < 4; ++t)
        bfr[t] = *(const bf16x8*)(W1T + ((ft0 + t) * 16 + r) * 32 + q * 8);

    // ---- cutoff * mask ----
    if (tid < NK) {
        float d = dR[n * NK + tid];
        float m = mask[n * NK + tid];
        s_cm[tid] = (d <= 5.0f) ? m : 0.0f;
    }

    float bias1[4];
    #pragma unroll
    for (int t = 0; t < 4; ++t) bias1[t] = b1[(ft0 + t) * 16 + r];

    // ---- stage 1: H = ssp(dRe @ W1 + b1), A-frags direct from global ----
    const float* dre_n = dRe + (size_t)n * (NK * 25);
    #pragma unroll
    for (int mt = 0; mt < 3; ++mt) {
        bf16x8 av8;
        if (q < 3) {
            float av[8];
            __builtin_memcpy(av, dre_n + (mt * 16 + r) * 25 + q * 8, 32);
            #pragma unroll
            for (int j = 0; j < 8; ++j) av8[j] = (__bf16)av[j];
        } else {
            float v = dre_n[(mt * 16 + r) * 25 + 24];
            av8[0] = (__bf16)v;
            #pragma unroll
            for (int j = 1; j < 8; ++j) av8[j] = (__bf16)0.0f;
        }
        #pragma unroll
        for (int t = 0; t < 4; ++t) {
            f32x4 zf; zf[0]=0.f; zf[1]=0.f; zf[2]=0.f; zf[3]=0.f;
            f32x4 h = __builtin_amdgcn_mfma_f32_16x16x32_bf16(av8, bfr[t], zf, 0, 0, 0);
            #pragma unroll
            for (int reg = 0; reg < 4; ++reg) {
                int k = mt * 16 + q * 4 + reg;
                s_H[k * HP + (ft0 + t) * 16 + r] = f2bs(sspf(h[reg] + bias1[t]));
            }
        }
    }

    // ---- write gathered rows to LDS (latency hidden under stage1) ----
    #pragma unroll
    for (int j = 0; j < 6; ++j)
        *(bf16x8*)(&s_yf[(kb + 8 * j) * YFP + sp * 8]) = g[j];

    __syncthreads();   // the ONLY barrier

    // ---- two passes over f-tile pairs: per pass byte-identical to round-4 ----
    #pragma unroll
    for (int p = 0; p < 2; ++p) {
        const int nt0 = ft0 + 2 * p;

        bf16x8 bw[2][4];
        #pragma unroll
        for (int t = 0; t < 2; ++t)
            #pragma unroll
            for (int ks = 0; ks < 4; ++ks)
                bw[t][ks] = *(const bf16x8*)(W2T + ((nt0 + t) * 16 + r) * NF + ks * 32 + q * 8);
        const float bias2a = b2[nt0 * 16 + r];
        const float bias2b = b2[nt0 * 16 + 16 + r];

        f32x4 acc[3][2];
        #pragma unroll
        for (int mt = 0; mt < 3; ++mt)
            #pragma unroll
            for (int t = 0; t < 2; ++t) { acc[mt][t][0]=0.f; acc[mt][t][1]=0.f; acc[mt][t][2]=0.f; acc[mt][t][3]=0.f; }

        #pragma unroll
        for (int ks = 0; ks < 4; ++ks) {
            #pragma unroll
            for (int mt = 0; mt < 3; ++mt) {
                bf16x8 ah = *(const bf16x8*)(&s_H[(mt * 16 + r) * HP + ks * 32 + q * 8]);
                acc[mt][0] = __builtin_amdgcn_mfma_f32_16x16x32_bf16(ah, bw[0][ks], acc[mt][0], 0, 0, 0);
                acc[mt][1] = __builtin_amdgcn_mfma_f32_16x16x32_bf16(ah, bw[1][ks], acc[mt][1], 0, 0, 0);
            }
        }

        float part0 = 0.f, part1 = 0.f;
        const int h0 = nt0 * 16 + r;
        #pragma unroll
        for (int mt = 0; mt < 3; ++mt) {
            #pragma unroll
            for (int reg = 0; reg < 4; ++reg) {
                int k = mt * 16 + q * 4 + reg;
                float cmk = s_cm[k];
                part0 += cmk * (acc[mt][0][reg] + bias2a) * bs2f(s_yf[k * YFP + h0]);
                part1 += cmk * (acc[mt][1][reg] + bias2b) * bs2f(s_yf[k * YFP + h0 + 16]);
            }
        }
        part0 += __shfl_xor(part0, 16);
        part0 += __shfl_xor(part0, 32);
        part1 += __shfl_xor(part1, 16);
        part1 += __shfl_xor(part1, 32);
        if (q == 0) {
            yout[(size_t)n * NF + h0]      = part0;
            yout[(size_t)n * NF + h0 + 16] = part1;
        }
    }
}

// ---- f2out: out = ssp(y @ Wf2o + b), MFMA, IN PLACE on the out buffer ----
__global__ __launch_bounds__(256) void f2out_mfma(
    const unsigned short* __restrict__ WoT,
    const float* __restrict__ bo,
    float* io)
{
    const int tid = threadIdx.x;
    const int w = tid >> 6;
    const int lane = tid & 63;
    const int r = lane & 15;
    const int q = lane >> 4;
    const int m0 = blockIdx.x * 64 + w * 16;
    const int row = m0 + r;
    const bool rv = (row < NA);

    f32x4 acc[8];
    #pragma unroll
    for (int nt = 0; nt < 8; ++nt) { acc[nt][0]=0.f; acc[nt][1]=0.f; acc[nt][2]=0.f; acc[nt][3]=0.f; }

    #pragma unroll
    for (int ks = 0; ks < 4; ++ks) {
        bf16x8 a;
        if (rv) {
            const float4* yp = (const float4*)(io + (size_t)row * NF + ks * 32 + q * 8);
            float4 v0 = yp[0], v1 = yp[1];
            a[0]=(__bf16)v0.x; a[1]=(__bf16)v0.y; a[2]=(__bf16)v0.z; a[3]=(__bf16)v0.w;
            a[4]=(__bf16)v1.x; a[5]=(__bf16)v1.y; a[6]=(__bf16)v1.z; a[7]=(__bf16)v1.w;
        } else {
            #pragma unroll
            for (int j = 0; j < 8; ++j) a[j] = (__bf16)0.0f;
        }
        #pragma unroll
        for (int nt = 0; nt < 8; ++nt) {
            bf16x8 b = *(const bf16x8*)(WoT + (nt * 16 + r) * NF + ks * 32 + q * 8);
            acc[nt] = __builtin_amdgcn_mfma_f32_16x16x32_bf16(a, b, acc[nt], 0, 0, 0);
        }
    }
    #pragma unroll
    for (int nt = 0; nt < 8; ++nt) {
        float bia = bo[nt * 16 + r];
        #pragma unroll
        for (int reg = 0; reg < 4; ++reg) {
            int orow = m0 + q * 4 + reg;
            if (orow < NA)
                io[(size_t)orow * NF + nt * 16 + r] = sspf(acc[nt][reg] + bia);
        }
    }
}

extern "C" void kernel_launch(void* const* d_in, const int* in_sizes, int n_in,
                              void* d_out, int out_size, void* d_ws, size_t ws_size,
                              hipStream_t stream)
{
    const float* x    = (const float*)d_in[0];
    const float* dR   = (const float*)d_in[1];
    const float* dRe  = (const float*)d_in[2];
    const float* mask = (const float*)d_in[3];
    const int*   nbr  = (const int*)d_in[4];
    const float* W1   = (const float*)d_in[5];
    const float* b1   = (const float*)d_in[6];
    const float* W2   = (const float*)d_in[7];
    const float* b2   = (const float*)d_in[8];
    const float* Wi2f = (const float*)d_in[9];
    const float* Wf2o = (const float*)d_in[10];
    const float* bf2o = (const float*)d_in[11];
    float* out = (float*)d_out;

    unsigned short* wsb = (unsigned short*)d_ws;
    unsigned short* W1T    = wsb;            // 4096 elems
    unsigned short* W2T    = wsb + 4096;     // 16384 elems
    unsigned short* WiT    = wsb + 20480;    // 16384 elems
    unsigned short* WoT    = wsb + 36864;    // 16384 elems
    unsigned short* yfeatb = wsb + 53248;    // 1,280,000 elems

    prep_weights<<<208, 256, 0, stream>>>(W1, W2, Wi2f, Wf2o, wsb);
    in2f_mfma<<<157, 256, 0, stream>>>(x, WiT, yfeatb);
    cfconv_d<<<NA, 128, 0, stream>>>(dR, dRe, mask, nbr, b1, b2,
                                     W1T, W2T, yfeatb, out);
    f2out_mfma<<<157, 256, 0, stream>>>(WoT, bf2o, out);
}